// Round 11
// baseline (331.583 us; speedup 1.0000x reference)
//
#include <hip/hip_runtime.h>
#include <hip/hip_bf16.h>

#define N_NODES 100000
#define N_EDGES 1600000
#define D_IN    256
#define D_OUT_T 512      // 8 heads * 64, concatenated
#define MPAD    100096   // 782 * 128

#define BM 128
#define BN 128
#define BK 64

#define NB_H2B 25000     // N_NODES*(D_IN/4)/256
#define NB_WCT 512       // 8*256*64/256
#define NB_DEG 6250      // N_EDGES/256

#define NPART 8
#define ROWS_PER_PART (N_NODES / NPART)   // 12500
#define FILL_BLOCKS 2048                  // 256 blocks per partition

#define AGG_BLOCKS 2048                   // 8192 waves = 256 CU x 32 (full residency)
#define NODES_PER_WAVE 13                 // 8192*13 = 106496 >= 100000

typedef __attribute__((ext_vector_type(4))) float f32x4;
typedef __attribute__((ext_vector_type(8))) short bf16x8;
typedef __attribute__((ext_vector_type(4))) unsigned short u16x4;

__device__ __forceinline__ float bf2f(unsigned short u) {
    union { unsigned int i; float f; } x; x.i = ((unsigned int)u) << 16; return x.f;
}
__device__ __forceinline__ unsigned short f2bf(float f) {
    union { float f; unsigned int i; } x; x.f = f;
    unsigned int i = x.i;
    return (unsigned short)((i + 0x7FFFu + ((i >> 16) & 1u)) >> 16);  // RNE
}
__device__ __forceinline__ f32x4 cv4(u16x4 v) {
    f32x4 r; r.x = bf2f(v.x); r.y = bf2f(v.y); r.z = bf2f(v.z); r.w = bf2f(v.w);
    return r;
}

// ---------------- fused preprocessing: h->bf16 | W->WcT | deg+rank ------------
// WcT[h*64+j][d] = W[h][d][j].
// deg pass: atomicAdd's RETURN VALUE is the edge's within-row rank — stored to
// rank[i] (coalesced). This makes the later CSR fill atomic-free (r7 insight).
__global__ void k_pre(const float* __restrict__ h, unsigned short* __restrict__ hb,
                      const float* __restrict__ W, unsigned short* __restrict__ WcT,
                      const int* __restrict__ erow, int* __restrict__ deg,
                      int* __restrict__ rank, int do_hb) {
    int b = blockIdx.x;
    if (b < NB_H2B) {
        if (!do_hb) return;
        int i = b * 256 + threadIdx.x;                 // 6.4M float4 groups
        f32x4 v = ((const f32x4*)h)[i];
        u16x4 o; o.x = f2bf(v.x); o.y = f2bf(v.y); o.z = f2bf(v.z); o.w = f2bf(v.w);
        ((u16x4*)hb)[i] = o;
    } else if (b < NB_H2B + NB_WCT) {
        int t = (b - NB_H2B) * 256 + threadIdx.x;      // 131072
        int hh = t >> 14;
        int rem = t & 16383;
        int d = rem >> 6;
        int j = rem & 63;
        WcT[(size_t)(hh * 64 + j) * 256 + d] = f2bf(W[t]);
    } else {
        int i = (b - NB_H2B - NB_WCT) * 256 + threadIdx.x;
        if (i < N_EDGES) rank[i] = atomicAdd(&deg[erow[i]], 1);
    }
}

// ---------------- ONE-kernel segment allocation (atomic base reservation) -----
// Segments need not be in row order (per-row sums are order-independent): each
// block local-scans its 256 degrees and reserves a contiguous region with one
// atomicAdd on a global counter.
__global__ __launch_bounds__(256) void k_scan(const int* __restrict__ deg,
                                              int* __restrict__ start,
                                              int* __restrict__ gcnt) {
    __shared__ int sm[256];
    __shared__ int sbase;
    int t = threadIdx.x, i = blockIdx.x * 256 + t;
    int v = (i < N_NODES) ? deg[i] : 0;
    sm[t] = v; __syncthreads();
    #pragma unroll
    for (int o = 1; o < 256; o <<= 1) {
        int x = (t >= o) ? sm[t - o] : 0;
        __syncthreads();
        sm[t] += x;
        __syncthreads();
    }
    if (t == 255) sbase = atomicAdd(gcnt, sm[255]);
    __syncthreads();
    if (i < N_NODES) start[i] = sbase + sm[t] - v;
}

// ---------------- CSR fill: ATOMIC-FREE, row-range partitioned (NPART=8) ------
// pos = start[r] + rank[i] is unique by construction -> plain store, no cursor
// atomics. Partition p = blockIdx&7 (XCD round-robin): partition p's colidx
// region is written from one XCD -> full-line writebacks (r2/r6: cross-XCD 4B
// scatter caused 16x write-amp). Edge re-reads (passes 2..8) hit LLC.
__global__ __launch_bounds__(256) void k_fill(const int* __restrict__ erow,
                                              const int* __restrict__ ecol,
                                              const int* __restrict__ rank,
                                              const int* __restrict__ start,
                                              int* __restrict__ colidx) {
    const int part = blockIdx.x & (NPART - 1);
    const int bi   = blockIdx.x >> 3;
    const int lo = part * ROWS_PER_PART;
    const int hi = lo + ROWS_PER_PART;
    const int stride = (FILL_BLOCKS / NPART) * 256;
    for (int i = bi * 256 + threadIdx.x; i < N_EDGES; i += stride) {
        int r = erow[i];
        if (r >= lo && r < hi)
            colidx[start[r] + rank[i]] = ecol[i];
    }
}

// ---------------- aggregation: persistent waves, 8-deep MLP -------------------
// r11: grid = 2048 blocks = 8192 waves = full residency cap (256 CU x 32).
// Wave g owns nodes [g*13, g*13+13): no block launch churn; every SIMD holds
// 8 waves for the whole kernel (r10 counters: occupancy 55% with 25000 short
// blocks was the suspected limiter of this latency-hiding-bound gather).
// Inner pipeline unchanged (r4 lesson: 8-deep beats 16-deep).
template <bool BF16SRC>
__global__ __launch_bounds__(256) void k_agg(const void* __restrict__ src,
                                             const int* __restrict__ start,
                                             const int* __restrict__ deg,
                                             const int* __restrict__ colidx,
                                             unsigned short* __restrict__ hagg) {
    int gw = blockIdx.x * 4 + (threadIdx.x >> 6);   // 0..8191
    int lane = threadIdx.x & 63;
    int n0 = gw * NODES_PER_WAVE;
    int n1 = n0 + NODES_PER_WAVE;
    if (n1 > N_NODES) n1 = N_NODES;
    const unsigned short* hb = (const unsigned short*)src;
    const float* hf = (const float*)src;
    for (int wid = n0; wid < n1; ++wid) {
        int s = start[wid];
        int d = deg[wid];
        int e = s + d;
        f32x4 acc[8] = {};
        int p = s;
        for (; p + 8 <= e; p += 8) {
            int c[8];
            #pragma unroll
            for (int j = 0; j < 8; ++j) c[j] = colidx[p + j];
            if constexpr (BF16SRC) {
                u16x4 v[8];
                #pragma unroll
                for (int j = 0; j < 8; ++j)
                    v[j] = *((const u16x4*)(hb + ((size_t)c[j] << 8)) + lane);
                #pragma unroll
                for (int j = 0; j < 8; ++j) acc[j] += cv4(v[j]);
            } else {
                f32x4 v[8];
                #pragma unroll
                for (int j = 0; j < 8; ++j)
                    v[j] = *((const f32x4*)(hf + ((size_t)c[j] << 8)) + lane);
                #pragma unroll
                for (int j = 0; j < 8; ++j) acc[j] += v[j];
            }
        }
        if (p + 4 <= e) {
            int c[4];
            #pragma unroll
            for (int j = 0; j < 4; ++j) c[j] = colidx[p + j];
            if constexpr (BF16SRC) {
                u16x4 v[4];
                #pragma unroll
                for (int j = 0; j < 4; ++j)
                    v[j] = *((const u16x4*)(hb + ((size_t)c[j] << 8)) + lane);
                #pragma unroll
                for (int j = 0; j < 4; ++j) acc[j] += cv4(v[j]);
            } else {
                f32x4 v[4];
                #pragma unroll
                for (int j = 0; j < 4; ++j)
                    v[j] = *((const f32x4*)(hf + ((size_t)c[j] << 8)) + lane);
                #pragma unroll
                for (int j = 0; j < 4; ++j) acc[j] += v[j];
            }
            p += 4;
        }
        for (; p < e; ++p) {
            int c = colidx[p];
            if constexpr (BF16SRC) {
                acc[0] += cv4(*((const u16x4*)(hb + ((size_t)c << 8)) + lane));
            } else {
                acc[0] += *((const f32x4*)(hf + ((size_t)c << 8)) + lane);
            }
        }
        #pragma unroll
        for (int j = 4; j < 8; ++j) acc[j - 4] += acc[j];
        acc[0] += acc[2]; acc[1] += acc[3]; acc[0] += acc[1];
        float inv = (d > 0) ? 1.0f / (float)d : 0.0f;
        u16x4 o;
        o.x = f2bf(acc[0].x * inv); o.y = f2bf(acc[0].y * inv);
        o.z = f2bf(acc[0].z * inv); o.w = f2bf(acc[0].w * inv);
        *((u16x4*)(hagg + ((size_t)wid << 8)) + lane) = o;
    }
}

// ---------------- GEMM: C[M x 512] = hagg[M x 256] * Wc[256 x 512] ----------------
// r3 geometry + r10 operand-swapped MFMA (neutral but fewer store insts):
// acc = mfma(b, a, acc) computes C^T in regs -> lane&15 = M, (lane>>4)*4+reg = N
// -> epilogue is 16 f32x4 stores.
// A = hagg row-major [MPAD][256] bf16; B = WcT row-major [512][256] bf16.
// 128x128 block tile, 4 waves (2x2), wave 64x64, BK=64, 16x16x32 bf16 MFMA.
// LDS tiles [rows][64] with 16B-chunk XOR swizzle (chunk ^= row&7): linear
// global_load_lds dest + inverse-swizzled global src + swizzled ds_read.
// 1D grid with XCD-chunk swizzle: the 4 N-blocks sharing an A panel are
// consecutive on the same XCD -> A fetched ~once from HBM.
__global__ __launch_bounds__(256, 2) void k_gemm(const unsigned short* __restrict__ A,
                                                 const unsigned short* __restrict__ B,
                                                 float* __restrict__ C, int M) {
    __shared__ __align__(16) unsigned short As[BM * BK];
    __shared__ __align__(16) unsigned short Bs[BN * BK];
    const int orig = blockIdx.x;                   // 3128 = 782*4, 3128%8==0
    const int wgid = (orig & 7) * (3128 / 8) + (orig >> 3);
    const int M0 = (wgid >> 2) * BM;
    const int N0 = (wgid & 3) * BN;
    const int tid  = threadIdx.x;
    const int wave = tid >> 6;
    const int lane = tid & 63;
    const int wm = (wave >> 1) * 64;
    const int wn = (wave & 1) * 64;

    f32x4 acc[4][4] = {};

    for (int kk = 0; kk < D_IN; kk += BK) {
        __syncthreads();  // previous-iteration LDS reads done before overwrite
        #pragma unroll
        for (int i = 0; i < 4; ++i) {  // stage A tile: 128 rows x 64 k
            int rbase = i * 32 + wave * 8;
            int r = rbase + (lane >> 3);
            int gc = (lane & 7) ^ (r & 7);  // inverse-swizzled source chunk
            const unsigned short* g = A + (size_t)(M0 + r) * D_IN + kk + gc * 8;
            __builtin_amdgcn_global_load_lds(
                (const __attribute__((address_space(1))) void*)g,
                (__attribute__((address_space(3))) void*)(As + rbase * 64), 16, 0, 0);
        }
        #pragma unroll
        for (int i = 0; i < 4; ++i) {  // stage B tile: 128 cols x 64 k
            int rbase = i * 32 + wave * 8;
            int r = rbase + (lane >> 3);
            int gc = (lane & 7) ^ (r & 7);
            const unsigned short* g = B + (size_t)(N0 + r) * D_IN + kk + gc * 8;
            __builtin_amdgcn_global_load_lds(
                (const __attribute__((address_space(1))) void*)g,
                (__attribute__((address_space(3))) void*)(Bs + rbase * 64), 16, 0, 0);
        }
        __syncthreads();

        #pragma unroll
        for (int ks = 0; ks < 2; ++ks) {
            bf16x8 a[4], b[4];
            #pragma unroll
            for (int m = 0; m < 4; ++m) {
                int r = wm + m * 16 + (lane & 15);
                int lc = (ks * 4 + (lane >> 4)) ^ (r & 7);  // swizzled read chunk
                a[m] = *(const bf16x8*)(As + r * 64 + lc * 8);
            }
            #pragma unroll
            for (int n = 0; n < 4; ++n) {
                int c = wn + n * 16 + (lane & 15);
                int lc = (ks * 4 + (lane >> 4)) ^ (c & 7);
                b[n] = *(const bf16x8*)(Bs + c * 64 + lc * 8);
            }
            #pragma unroll
            for (int m = 0; m < 4; ++m)
                #pragma unroll
                for (int n = 0; n < 4; ++n)
                    acc[m][n] = __builtin_amdgcn_mfma_f32_16x16x32_bf16(
                        b[n], a[m], acc[m][n], 0, 0, 0);   // SWAPPED -> C^T regs
        }
    }

    // Swapped C/D layout: M = lane&15, N = (lane>>4)*4 + reg -> f32x4 store.
    #pragma unroll
    for (int m = 0; m < 4; ++m) {
        int row = M0 + wm + m * 16 + (lane & 15);
        if (row < M) {
            #pragma unroll
            for (int n = 0; n < 4; ++n) {
                int col = N0 + wn + n * 16 + (lane >> 4) * 4;
                *(f32x4*)(C + (size_t)row * D_OUT_T + col) = acc[m][n];
            }
        }
    }
}

extern "C" void kernel_launch(void* const* d_in, const int* in_sizes, int n_in,
                              void* d_out, int out_size, void* d_ws, size_t ws_size,
                              hipStream_t stream) {
    const float* h  = (const float*)d_in[0];
    const float* W  = (const float*)d_in[1];
    const int* erow = (const int*)d_in[2];
    const int* ecol = erow + N_EDGES;
    float* out = (float*)d_out;

    char* base = (char*)d_ws;
    size_t off = 0;
    auto alloc = [&](size_t b) {
        char* p = base + off;
        off += (b + 255) & ~(size_t)255;
        return p;
    };
    int* deg    = (int*)alloc((N_NODES + 1) * sizeof(int));  // [N] = global cursor
    int* start  = (int*)alloc(N_NODES * sizeof(int));
    int* rank   = (int*)alloc((size_t)N_EDGES * sizeof(int));
    int* colidx = (int*)alloc((size_t)N_EDGES * sizeof(int));
    unsigned short* WcT  = (unsigned short*)alloc((size_t)D_OUT_T * D_IN * 2);
    unsigned short* hagg = (unsigned short*)alloc((size_t)MPAD * D_IN * 2);
    unsigned short* hb   = (unsigned short*)alloc((size_t)N_NODES * D_IN * 2);
    bool use_hb = (off <= ws_size);  // fall back to fp32 gather if ws too small

    hipMemsetAsync(deg, 0, (N_NODES + 1) * sizeof(int), stream);

    k_pre<<<NB_H2B + NB_WCT + NB_DEG, 256, 0, stream>>>(
        h, hb, W, WcT, erow, deg, rank, use_hb ? 1 : 0);

    const int NB = (N_NODES + 255) / 256;  // 391
    k_scan<<<NB, 256, 0, stream>>>(deg, start, deg + N_NODES);
    k_fill<<<FILL_BLOCKS, 256, 0, stream>>>(erow, ecol, rank, start, colidx);

    if (use_hb)
        k_agg<true><<<AGG_BLOCKS, 256, 0, stream>>>(hb, start, deg, colidx, hagg);
    else
        k_agg<false><<<AGG_BLOCKS, 256, 0, stream>>>(h, start, deg, colidx, hagg);

    k_gemm<<<MPAD / BM * 4, 256, 0, stream>>>(hagg, WcT, out, N_NODES);
}

// Round 12
// 309.034 us; speedup vs baseline: 1.0730x; 1.0730x over previous
//
#include <hip/hip_runtime.h>
#include <hip/hip_bf16.h>

#define N_NODES 100000
#define N_EDGES 1600000
#define D_IN    256
#define D_OUT_T 512      // 8 heads * 64, concatenated
#define MPAD    100096   // 782 * 128

#define BM 128
#define BN 128
#define BK 64

#define NB_H2B 25000     // N_NODES*(D_IN/4)/256
#define NB_WCT 512       // 8*256*64/256
#define NB_DEG 6250      // N_EDGES/256

#define NPART 8
#define ROWS_PER_PART (N_NODES / NPART)   // 12500
#define FILL_BLOCKS 2048                  // 256 blocks per partition

typedef __attribute__((ext_vector_type(4))) float f32x4;
typedef __attribute__((ext_vector_type(8))) short bf16x8;
typedef __attribute__((ext_vector_type(4))) unsigned short u16x4;
typedef __attribute__((ext_vector_type(8))) unsigned short u16x8;

__device__ __forceinline__ float bf2f(unsigned short u) {
    union { unsigned int i; float f; } x; x.i = ((unsigned int)u) << 16; return x.f;
}
__device__ __forceinline__ unsigned short f2bf(float f) {
    union { float f; unsigned int i; } x; x.f = f;
    unsigned int i = x.i;
    return (unsigned short)((i + 0x7FFFu + ((i >> 16) & 1u)) >> 16);  // RNE
}
__device__ __forceinline__ f32x4 cv4(u16x4 v) {
    f32x4 r; r.x = bf2f(v.x); r.y = bf2f(v.y); r.z = bf2f(v.z); r.w = bf2f(v.w);
    return r;
}

// ---------------- fused preprocessing: h->bf16 | W->WcT | deg+rank ------------
// WcT[h*64+j][d] = W[h][d][j].
// deg pass: atomicAdd's RETURN VALUE is the edge's within-row rank — stored to
// rank[i] (coalesced). This makes the later CSR fill atomic-free (r7 insight).
__global__ void k_pre(const float* __restrict__ h, unsigned short* __restrict__ hb,
                      const float* __restrict__ W, unsigned short* __restrict__ WcT,
                      const int* __restrict__ erow, int* __restrict__ deg,
                      int* __restrict__ rank, int do_hb) {
    int b = blockIdx.x;
    if (b < NB_H2B) {
        if (!do_hb) return;
        int i = b * 256 + threadIdx.x;                 // 6.4M float4 groups
        f32x4 v = ((const f32x4*)h)[i];
        u16x4 o; o.x = f2bf(v.x); o.y = f2bf(v.y); o.z = f2bf(v.z); o.w = f2bf(v.w);
        ((u16x4*)hb)[i] = o;
    } else if (b < NB_H2B + NB_WCT) {
        int t = (b - NB_H2B) * 256 + threadIdx.x;      // 131072
        int hh = t >> 14;
        int rem = t & 16383;
        int d = rem >> 6;
        int j = rem & 63;
        WcT[(size_t)(hh * 64 + j) * 256 + d] = f2bf(W[t]);
    } else {
        int i = (b - NB_H2B - NB_WCT) * 256 + threadIdx.x;
        if (i < N_EDGES) rank[i] = atomicAdd(&deg[erow[i]], 1);
    }
}

// ---------------- ONE-kernel segment allocation (atomic base reservation) -----
__global__ __launch_bounds__(256) void k_scan(const int* __restrict__ deg,
                                              int* __restrict__ start,
                                              int* __restrict__ gcnt) {
    __shared__ int sm[256];
    __shared__ int sbase;
    int t = threadIdx.x, i = blockIdx.x * 256 + t;
    int v = (i < N_NODES) ? deg[i] : 0;
    sm[t] = v; __syncthreads();
    #pragma unroll
    for (int o = 1; o < 256; o <<= 1) {
        int x = (t >= o) ? sm[t - o] : 0;
        __syncthreads();
        sm[t] += x;
        __syncthreads();
    }
    if (t == 255) sbase = atomicAdd(gcnt, sm[255]);
    __syncthreads();
    if (i < N_NODES) start[i] = sbase + sm[t] - v;
}

// ---------------- CSR fill: ATOMIC-FREE, row-range partitioned (NPART=8) ------
// pos = start[r] + rank[i] is unique by construction -> plain store.
// Partition p = blockIdx&7 (XCD round-robin) -> colidx region written from one
// XCD -> full-line writebacks (r2/r6 evidence). Edge re-reads hit LLC.
__global__ __launch_bounds__(256) void k_fill(const int* __restrict__ erow,
                                              const int* __restrict__ ecol,
                                              const int* __restrict__ rank,
                                              const int* __restrict__ start,
                                              int* __restrict__ colidx) {
    const int part = blockIdx.x & (NPART - 1);
    const int bi   = blockIdx.x >> 3;
    const int lo = part * ROWS_PER_PART;
    const int hi = lo + ROWS_PER_PART;
    const int stride = (FILL_BLOCKS / NPART) * 256;
    for (int i = bi * 256 + threadIdx.x; i < N_EDGES; i += stride) {
        int r = erow[i];
        if (r >= lo && r < hi)
            colidx[start[r] + rank[i]] = ecol[i];
    }
}

// ---------------- aggregation: one wave per node, PAIRED half-wave gather -----
// r12: two edges per wave-load instruction. Lanes 0-31 gather row c_even at
// 16 B/lane (bf16x8), lanes 32-63 gather row c_odd. Same bytes and cache lines
// per row as r10's 8 B/lane version, but HALF the VMEM instructions and 2x rows
// in flight per wave (r10 counters: nothing saturated -> issue/latency bound).
// Lane covers d-chunk [sub*8, sub*8+8); final __shfl_xor(32) combines halves;
// lanes 0-31 store 16 B. Chunked 8/4/2/1-pair loops keep 8-deep load chains.
// Grid: r10-proven 25000 blocks (r11 persistent-wave variant regressed).
template <bool BF16SRC>
__global__ __launch_bounds__(256) void k_agg(const void* __restrict__ src,
                                             const int* __restrict__ start,
                                             const int* __restrict__ deg,
                                             const int* __restrict__ colidx,
                                             unsigned short* __restrict__ hagg) {
    int wid = blockIdx.x * 4 + (threadIdx.x >> 6);
    int lane = threadIdx.x & 63;
    if (wid >= N_NODES) return;
    int s = start[wid];
    int d = deg[wid];
    int e = s + d;

    if constexpr (BF16SRC) {
        const unsigned short* hb = (const unsigned short*)src;
        const int half = lane >> 5;       // which edge of the pair
        const int sub  = lane & 31;       // d-chunk: elements [sub*8, sub*8+8)
        float acc[8] = {};
        int p = s;

        auto pairs = [&](int np) {        // process np pairs from p (np edges*2)
            #pragma unroll 8
            for (int k = 0; k < np; ++k) {
                int c0 = colidx[p + 2 * k];
                int c1 = colidx[p + 2 * k + 1];
                int c = half ? c1 : c0;
                bf16x8 v = *(const bf16x8*)(hb + ((size_t)c << 8) + sub * 8);
                #pragma unroll
                for (int j = 0; j < 8; ++j)
                    acc[j] += bf2f(((unsigned short)v[j]));
            }
        };
        // chunked: 8 pairs, then 4, 2, 1 — preserves deep load chains
        for (; p + 16 <= e; p += 16) pairs(8);
        if (p + 8 <= e) { pairs(4); p += 8; }
        if (p + 4 <= e) { pairs(2); p += 4; }
        if (p + 2 <= e) { pairs(1); p += 2; }
        if (p < e) {                       // odd tail: both halves load, half0 adds
            int c = colidx[p];
            bf16x8 v = *(const bf16x8*)(hb + ((size_t)c << 8) + sub * 8);
            if (half == 0) {
                #pragma unroll
                for (int j = 0; j < 8; ++j)
                    acc[j] += bf2f(((unsigned short)v[j]));
            }
        }
        float inv = (d > 0) ? 1.0f / (float)d : 0.0f;
        u16x8 o;
        #pragma unroll
        for (int j = 0; j < 8; ++j) {
            float tot = acc[j] + __shfl_xor(acc[j], 32);
            o[j] = f2bf(tot * inv);
        }
        if (half == 0)
            *(u16x8*)(hagg + ((size_t)wid << 8) + sub * 8) = o;
    } else {
        // fp32 fallback (ws too small): r10 full-wave 8-deep path
        const float* hf = (const float*)src;
        f32x4 acc[8] = {};
        int p = s;
        for (; p + 8 <= e; p += 8) {
            int c[8];
            #pragma unroll
            for (int j = 0; j < 8; ++j) c[j] = colidx[p + j];
            f32x4 v[8];
            #pragma unroll
            for (int j = 0; j < 8; ++j)
                v[j] = *((const f32x4*)(hf + ((size_t)c[j] << 8)) + lane);
            #pragma unroll
            for (int j = 0; j < 8; ++j) acc[j] += v[j];
        }
        for (; p < e; ++p)
            acc[0] += *((const f32x4*)(hf + ((size_t)colidx[p] << 8)) + lane);
        #pragma unroll
        for (int j = 4; j < 8; ++j) acc[j - 4] += acc[j];
        acc[0] += acc[2]; acc[1] += acc[3]; acc[0] += acc[1];
        float inv = (d > 0) ? 1.0f / (float)d : 0.0f;
        u16x4 o;
        o.x = f2bf(acc[0].x * inv); o.y = f2bf(acc[0].y * inv);
        o.z = f2bf(acc[0].z * inv); o.w = f2bf(acc[0].w * inv);
        *((u16x4*)(hagg + ((size_t)wid << 8)) + lane) = o;
    }
}

// ---------------- GEMM: C[M x 512] = hagg[M x 256] * Wc[256 x 512] ----------------
// r3 geometry + r10 operand-swapped MFMA: acc = mfma(b, a, acc) -> C^T regs ->
// lane&15 = M, (lane>>4)*4+reg = N -> epilogue is 16 f32x4 stores.
// 128x128 block tile, 4 waves (2x2), wave 64x64, BK=64, 16x16x32 bf16 MFMA.
// LDS [rows][64] with 16B-chunk XOR swizzle (chunk ^= row&7), both-sides.
// 1D grid with XCD-chunk swizzle: 4 N-blocks of an A panel share an XCD.
__global__ __launch_bounds__(256, 2) void k_gemm(const unsigned short* __restrict__ A,
                                                 const unsigned short* __restrict__ B,
                                                 float* __restrict__ C, int M) {
    __shared__ __align__(16) unsigned short As[BM * BK];
    __shared__ __align__(16) unsigned short Bs[BN * BK];
    const int orig = blockIdx.x;                   // 3128 = 782*4, 3128%8==0
    const int wgid = (orig & 7) * (3128 / 8) + (orig >> 3);
    const int M0 = (wgid >> 2) * BM;
    const int N0 = (wgid & 3) * BN;
    const int tid  = threadIdx.x;
    const int wave = tid >> 6;
    const int lane = tid & 63;
    const int wm = (wave >> 1) * 64;
    const int wn = (wave & 1) * 64;

    f32x4 acc[4][4] = {};

    for (int kk = 0; kk < D_IN; kk += BK) {
        __syncthreads();  // previous-iteration LDS reads done before overwrite
        #pragma unroll
        for (int i = 0; i < 4; ++i) {  // stage A tile: 128 rows x 64 k
            int rbase = i * 32 + wave * 8;
            int r = rbase + (lane >> 3);
            int gc = (lane & 7) ^ (r & 7);  // inverse-swizzled source chunk
            const unsigned short* g = A + (size_t)(M0 + r) * D_IN + kk + gc * 8;
            __builtin_amdgcn_global_load_lds(
                (const __attribute__((address_space(1))) void*)g,
                (__attribute__((address_space(3))) void*)(As + rbase * 64), 16, 0, 0);
        }
        #pragma unroll
        for (int i = 0; i < 4; ++i) {  // stage B tile: 128 cols x 64 k
            int rbase = i * 32 + wave * 8;
            int r = rbase + (lane >> 3);
            int gc = (lane & 7) ^ (r & 7);
            const unsigned short* g = B + (size_t)(N0 + r) * D_IN + kk + gc * 8;
            __builtin_amdgcn_global_load_lds(
                (const __attribute__((address_space(1))) void*)g,
                (__attribute__((address_space(3))) void*)(Bs + rbase * 64), 16, 0, 0);
        }
        __syncthreads();

        #pragma unroll
        for (int ks = 0; ks < 2; ++ks) {
            bf16x8 a[4], b[4];
            #pragma unroll
            for (int m = 0; m < 4; ++m) {
                int r = wm + m * 16 + (lane & 15);
                int lc = (ks * 4 + (lane >> 4)) ^ (r & 7);  // swizzled read chunk
                a[m] = *(const bf16x8*)(As + r * 64 + lc * 8);
            }
            #pragma unroll
            for (int n = 0; n < 4; ++n) {
                int c = wn + n * 16 + (lane & 15);
                int lc = (ks * 4 + (lane >> 4)) ^ (c & 7);
                b[n] = *(const bf16x8*)(Bs + c * 64 + lc * 8);
            }
            #pragma unroll
            for (int m = 0; m < 4; ++m)
                #pragma unroll
                for (int n = 0; n < 4; ++n)
                    acc[m][n] = __builtin_amdgcn_mfma_f32_16x16x32_bf16(
                        b[n], a[m], acc[m][n], 0, 0, 0);   // SWAPPED -> C^T regs
        }
    }

    // Swapped C/D layout: M = lane&15, N = (lane>>4)*4 + reg -> f32x4 store.
    #pragma unroll
    for (int m = 0; m < 4; ++m) {
        int row = M0 + wm + m * 16 + (lane & 15);
        if (row < M) {
            #pragma unroll
            for (int n = 0; n < 4; ++n) {
                int col = N0 + wn + n * 16 + (lane >> 4) * 4;
                *(f32x4*)(C + (size_t)row * D_OUT_T + col) = acc[m][n];
            }
        }
    }
}

extern "C" void kernel_launch(void* const* d_in, const int* in_sizes, int n_in,
                              void* d_out, int out_size, void* d_ws, size_t ws_size,
                              hipStream_t stream) {
    const float* h  = (const float*)d_in[0];
    const float* W  = (const float*)d_in[1];
    const int* erow = (const int*)d_in[2];
    const int* ecol = erow + N_EDGES;
    float* out = (float*)d_out;

    char* base = (char*)d_ws;
    size_t off = 0;
    auto alloc = [&](size_t b) {
        char* p = base + off;
        off += (b + 255) & ~(size_t)255;
        return p;
    };
    int* deg    = (int*)alloc((N_NODES + 1) * sizeof(int));  // [N] = global cursor
    int* start  = (int*)alloc(N_NODES * sizeof(int));
    int* rank   = (int*)alloc((size_t)N_EDGES * sizeof(int));
    int* colidx = (int*)alloc((size_t)N_EDGES * sizeof(int));
    unsigned short* WcT  = (unsigned short*)alloc((size_t)D_OUT_T * D_IN * 2);
    unsigned short* hagg = (unsigned short*)alloc((size_t)MPAD * D_IN * 2);
    unsigned short* hb   = (unsigned short*)alloc((size_t)N_NODES * D_IN * 2);
    bool use_hb = (off <= ws_size);  // fall back to fp32 gather if ws too small

    hipMemsetAsync(deg, 0, (N_NODES + 1) * sizeof(int), stream);

    k_pre<<<NB_H2B + NB_WCT + NB_DEG, 256, 0, stream>>>(
        h, hb, W, WcT, erow, deg, rank, use_hb ? 1 : 0);

    const int NB = (N_NODES + 255) / 256;  // 391
    k_scan<<<NB, 256, 0, stream>>>(deg, start, deg + N_NODES);
    k_fill<<<FILL_BLOCKS, 256, 0, stream>>>(erow, ecol, rank, start, colidx);

    if (use_hb)
        k_agg<true><<<(N_NODES + 3) / 4, 256, 0, stream>>>(hb, start, deg, colidx, hagg);
    else
        k_agg<false><<<(N_NODES + 3) / 4, 256, 0, stream>>>(h, start, deg, colidx, hagg);

    k_gemm<<<MPAD / BM * 4, 256, 0, stream>>>(hagg, WcT, out, N_NODES);
}

// Round 13
// 308.022 us; speedup vs baseline: 1.0765x; 1.0033x over previous
//
#include <hip/hip_runtime.h>
#include <hip/hip_bf16.h>

#define N_NODES 100000
#define N_EDGES 1600000
#define D_IN    256
#define D_OUT_T 512      // 8 heads * 64, concatenated
#define MPAD    100096   // 782 * 128

#define BM 128
#define BN 128
#define BK 64

#define NB_H2B 25000     // N_NODES*(D_IN/4)/256
#define NB_WCT 512       // 8*256*64/256
#define NB_DEG 6250      // N_EDGES/256

#define NPART 8
#define ROWS_PER_PART (N_NODES / NPART)   // 12500
#define FILL_BLOCKS 2048                  // 256 blocks per partition

typedef __attribute__((ext_vector_type(4))) float f32x4;
typedef __attribute__((ext_vector_type(8))) short bf16x8;
typedef __attribute__((ext_vector_type(4))) unsigned short u16x4;
typedef __attribute__((ext_vector_type(8))) unsigned short u16x8;

__device__ __forceinline__ float bf2f(unsigned short u) {
    union { unsigned int i; float f; } x; x.i = ((unsigned int)u) << 16; return x.f;
}
__device__ __forceinline__ unsigned short f2bf(float f) {
    union { float f; unsigned int i; } x; x.f = f;
    unsigned int i = x.i;
    return (unsigned short)((i + 0x7FFFu + ((i >> 16) & 1u)) >> 16);  // RNE
}

// ---------------- degree + rank ONLY (critical path to scan) ------------------
// r13: split from the old fused k_pre so k_scan doesn't wait on the 25000 h2b
// blocks. rank[i] = atomicAdd return = within-row rank (r7 insight).
__global__ __launch_bounds__(256) void k_deg(const int* __restrict__ erow,
                                             int* __restrict__ deg,
                                             int* __restrict__ rank) {
    int i = blockIdx.x * 256 + threadIdx.x;
    if (i < N_EDGES) rank[i] = atomicAdd(&deg[erow[i]], 1);
}

// ---------------- ONE-kernel segment allocation (atomic base reservation) -----
__global__ __launch_bounds__(256) void k_scan(const int* __restrict__ deg,
                                              int* __restrict__ start,
                                              int* __restrict__ gcnt) {
    __shared__ int sm[256];
    __shared__ int sbase;
    int t = threadIdx.x, i = blockIdx.x * 256 + t;
    int v = (i < N_NODES) ? deg[i] : 0;
    sm[t] = v; __syncthreads();
    #pragma unroll
    for (int o = 1; o < 256; o <<= 1) {
        int x = (t >= o) ? sm[t - o] : 0;
        __syncthreads();
        sm[t] += x;
        __syncthreads();
    }
    if (t == 255) sbase = atomicAdd(gcnt, sm[255]);
    __syncthreads();
    if (i < N_NODES) start[i] = sbase + sm[t] - v;
}

// ---------------- FUSED: CSR fill | h->bf16 | W->WcT --------------------------
// Blocks 0..2047: atomic-free fill (pos = start[r]+rank[i]), partition =
// blockIdx&7 (XCD affinity, r2/r6 write-amp lesson). Blocks 2048+: h2b
// streaming + WcT transpose — independent of scan, fused here so their
// streaming overlaps fill's latency-bound scatter instead of serializing
// ahead of it (r13 structural change).
__global__ __launch_bounds__(256) void k_fillpre(const int* __restrict__ erow,
                                                 const int* __restrict__ ecol,
                                                 const int* __restrict__ rank,
                                                 const int* __restrict__ start,
                                                 int* __restrict__ colidx,
                                                 const float* __restrict__ h,
                                                 unsigned short* __restrict__ hb,
                                                 const float* __restrict__ W,
                                                 unsigned short* __restrict__ WcT,
                                                 int do_hb) {
    int b = blockIdx.x;
    if (b < FILL_BLOCKS) {
        const int part = b & (NPART - 1);
        const int bi   = b >> 3;
        const int lo = part * ROWS_PER_PART;
        const int hi = lo + ROWS_PER_PART;
        const int stride = (FILL_BLOCKS / NPART) * 256;
        for (int i = bi * 256 + threadIdx.x; i < N_EDGES; i += stride) {
            int r = erow[i];
            if (r >= lo && r < hi)
                colidx[start[r] + rank[i]] = ecol[i];
        }
    } else if (b < FILL_BLOCKS + NB_H2B) {
        if (!do_hb) return;
        int i = (b - FILL_BLOCKS) * 256 + threadIdx.x;   // 6.4M float4 groups
        f32x4 v = ((const f32x4*)h)[i];
        u16x4 o; o.x = f2bf(v.x); o.y = f2bf(v.y); o.z = f2bf(v.z); o.w = f2bf(v.w);
        ((u16x4*)hb)[i] = o;
    } else {
        int t = (b - FILL_BLOCKS - NB_H2B) * 256 + threadIdx.x;  // 131072
        int hh = t >> 14;
        int rem = t & 16383;
        int d = rem >> 6;
        int j = rem & 63;
        WcT[(size_t)(hh * 64 + j) * 256 + d] = f2bf(W[t]);
    }
}

// ---------------- aggregation: one wave per node, PAIRED half-wave gather -----
// r12-proven (114us): two edges per wave-load. Lanes 0-31 gather row c_even at
// 16 B/lane (bf16x8), lanes 32-63 row c_odd; __shfl_xor(32) combines; lanes
// 0-31 store 16 B. 8/4/2/1-pair chunking keeps 8-deep load chains.
// r11/r4 lessons: persistent waves and 16-deep both regressed — keep this form.
template <bool BF16SRC>
__global__ __launch_bounds__(256) void k_agg(const void* __restrict__ src,
                                             const int* __restrict__ start,
                                             const int* __restrict__ deg,
                                             const int* __restrict__ colidx,
                                             unsigned short* __restrict__ hagg) {
    int wid = blockIdx.x * 4 + (threadIdx.x >> 6);
    int lane = threadIdx.x & 63;
    if (wid >= N_NODES) return;
    int s = start[wid];
    int d = deg[wid];
    int e = s + d;

    if constexpr (BF16SRC) {
        const unsigned short* hb = (const unsigned short*)src;
        const int half = lane >> 5;       // which edge of the pair
        const int sub  = lane & 31;       // d-chunk: elements [sub*8, sub*8+8)
        float acc[8] = {};
        int p = s;

        auto pairs = [&](int np) {        // process np pairs from p
            #pragma unroll 8
            for (int k = 0; k < np; ++k) {
                int c0 = colidx[p + 2 * k];
                int c1 = colidx[p + 2 * k + 1];
                int c = half ? c1 : c0;
                bf16x8 v = *(const bf16x8*)(hb + ((size_t)c << 8) + sub * 8);
                #pragma unroll
                for (int j = 0; j < 8; ++j)
                    acc[j] += bf2f(((unsigned short)v[j]));
            }
        };
        for (; p + 16 <= e; p += 16) pairs(8);
        if (p + 8 <= e) { pairs(4); p += 8; }
        if (p + 4 <= e) { pairs(2); p += 4; }
        if (p + 2 <= e) { pairs(1); p += 2; }
        if (p < e) {                       // odd tail: half0 adds
            int c = colidx[p];
            bf16x8 v = *(const bf16x8*)(hb + ((size_t)c << 8) + sub * 8);
            if (half == 0) {
                #pragma unroll
                for (int j = 0; j < 8; ++j)
                    acc[j] += bf2f(((unsigned short)v[j]));
            }
        }
        float inv = (d > 0) ? 1.0f / (float)d : 0.0f;
        u16x8 o;
        #pragma unroll
        for (int j = 0; j < 8; ++j) {
            float tot = acc[j] + __shfl_xor(acc[j], 32);
            o[j] = f2bf(tot * inv);
        }
        if (half == 0)
            *(u16x8*)(hagg + ((size_t)wid << 8) + sub * 8) = o;
    } else {
        // fp32 fallback (ws too small): full-wave 8-deep path
        const float* hf = (const float*)src;
        f32x4 acc[8] = {};
        int p = s;
        for (; p + 8 <= e; p += 8) {
            int c[8];
            #pragma unroll
            for (int j = 0; j < 8; ++j) c[j] = colidx[p + j];
            f32x4 v[8];
            #pragma unroll
            for (int j = 0; j < 8; ++j)
                v[j] = *((const f32x4*)(hf + ((size_t)c[j] << 8)) + lane);
            #pragma unroll
            for (int j = 0; j < 8; ++j) acc[j] += v[j];
        }
        for (; p < e; ++p)
            acc[0] += *((const f32x4*)(hf + ((size_t)colidx[p] << 8)) + lane);
        #pragma unroll
        for (int j = 4; j < 8; ++j) acc[j - 4] += acc[j];
        acc[0] += acc[2]; acc[1] += acc[3]; acc[0] += acc[1];
        float inv = (d > 0) ? 1.0f / (float)d : 0.0f;
        u16x4 o;
        o.x = f2bf(acc[0].x * inv); o.y = f2bf(acc[0].y * inv);
        o.z = f2bf(acc[0].z * inv); o.w = f2bf(acc[0].w * inv);
        *((u16x4*)(hagg + ((size_t)wid << 8)) + lane) = o;
    }
}

// ---------------- GEMM: C[M x 512] = hagg[M x 256] * Wc[256 x 512] ----------------
// r3 geometry + r10 operand-swapped MFMA (C^T regs -> 16 f32x4 stores).
// r13 change: __launch_bounds__(256,3) -> 3 blocks/CU (was 2). More resident
// waves to hide the per-iteration vmcnt(0)+barrier drain; <=170 VGPR so no
// spill risk. LDS 32KB x 3 = 96KB OK.
// 128x128 block tile, 4 waves (2x2), wave 64x64, BK=64, 16x16x32 bf16 MFMA.
// LDS [rows][64] with 16B-chunk XOR swizzle (chunk ^= row&7), both-sides.
// 1D grid with XCD-chunk swizzle: 4 N-blocks of an A panel share an XCD.
__global__ __launch_bounds__(256, 3) void k_gemm(const unsigned short* __restrict__ A,
                                                 const unsigned short* __restrict__ B,
                                                 float* __restrict__ C, int M) {
    __shared__ __align__(16) unsigned short As[BM * BK];
    __shared__ __align__(16) unsigned short Bs[BN * BK];
    const int orig = blockIdx.x;                   // 3128 = 782*4, 3128%8==0
    const int wgid = (orig & 7) * (3128 / 8) + (orig >> 3);
    const int M0 = (wgid >> 2) * BM;
    const int N0 = (wgid & 3) * BN;
    const int tid  = threadIdx.x;
    const int wave = tid >> 6;
    const int lane = tid & 63;
    const int wm = (wave >> 1) * 64;
    const int wn = (wave & 1) * 64;

    f32x4 acc[4][4] = {};

    for (int kk = 0; kk < D_IN; kk += BK) {
        __syncthreads();  // previous-iteration LDS reads done before overwrite
        #pragma unroll
        for (int i = 0; i < 4; ++i) {  // stage A tile: 128 rows x 64 k
            int rbase = i * 32 + wave * 8;
            int r = rbase + (lane >> 3);
            int gc = (lane & 7) ^ (r & 7);  // inverse-swizzled source chunk
            const unsigned short* g = A + (size_t)(M0 + r) * D_IN + kk + gc * 8;
            __builtin_amdgcn_global_load_lds(
                (const __attribute__((address_space(1))) void*)g,
                (__attribute__((address_space(3))) void*)(As + rbase * 64), 16, 0, 0);
        }
        #pragma unroll
        for (int i = 0; i < 4; ++i) {  // stage B tile: 128 cols x 64 k
            int rbase = i * 32 + wave * 8;
            int r = rbase + (lane >> 3);
            int gc = (lane & 7) ^ (r & 7);
            const unsigned short* g = B + (size_t)(N0 + r) * D_IN + kk + gc * 8;
            __builtin_amdgcn_global_load_lds(
                (const __attribute__((address_space(1))) void*)g,
                (__attribute__((address_space(3))) void*)(Bs + rbase * 64), 16, 0, 0);
        }
        __syncthreads();

        #pragma unroll
        for (int ks = 0; ks < 2; ++ks) {
            bf16x8 a[4], b[4];
            #pragma unroll
            for (int m = 0; m < 4; ++m) {
                int r = wm + m * 16 + (lane & 15);
                int lc = (ks * 4 + (lane >> 4)) ^ (r & 7);  // swizzled read chunk
                a[m] = *(const bf16x8*)(As + r * 64 + lc * 8);
            }
            #pragma unroll
            for (int n = 0; n < 4; ++n) {
                int c = wn + n * 16 + (lane & 15);
                int lc = (ks * 4 + (lane >> 4)) ^ (c & 7);
                b[n] = *(const bf16x8*)(Bs + c * 64 + lc * 8);
            }
            #pragma unroll
            for (int m = 0; m < 4; ++m)
                #pragma unroll
                for (int n = 0; n < 4; ++n)
                    acc[m][n] = __builtin_amdgcn_mfma_f32_16x16x32_bf16(
                        b[n], a[m], acc[m][n], 0, 0, 0);   // SWAPPED -> C^T regs
        }
    }

    // Swapped C/D layout: M = lane&15, N = (lane>>4)*4 + reg -> f32x4 store.
    #pragma unroll
    for (int m = 0; m < 4; ++m) {
        int row = M0 + wm + m * 16 + (lane & 15);
        if (row < M) {
            #pragma unroll
            for (int n = 0; n < 4; ++n) {
                int col = N0 + wn + n * 16 + (lane >> 4) * 4;
                *(f32x4*)(C + (size_t)row * D_OUT_T + col) = acc[m][n];
            }
        }
    }
}

extern "C" void kernel_launch(void* const* d_in, const int* in_sizes, int n_in,
                              void* d_out, int out_size, void* d_ws, size_t ws_size,
                              hipStream_t stream) {
    const float* h  = (const float*)d_in[0];
    const float* W  = (const float*)d_in[1];
    const int* erow = (const int*)d_in[2];
    const int* ecol = erow + N_EDGES;
    float* out = (float*)d_out;

    char* base = (char*)d_ws;
    size_t off = 0;
    auto alloc = [&](size_t b) {
        char* p = base + off;
        off += (b + 255) & ~(size_t)255;
        return p;
    };
    int* deg    = (int*)alloc((N_NODES + 1) * sizeof(int));  // [N] = global cursor
    int* start  = (int*)alloc(N_NODES * sizeof(int));
    int* rank   = (int*)alloc((size_t)N_EDGES * sizeof(int));
    int* colidx = (int*)alloc((size_t)N_EDGES * sizeof(int));
    unsigned short* WcT  = (unsigned short*)alloc((size_t)D_OUT_T * D_IN * 2);
    unsigned short* hagg = (unsigned short*)alloc((size_t)MPAD * D_IN * 2);
    unsigned short* hb   = (unsigned short*)alloc((size_t)N_NODES * D_IN * 2);
    bool use_hb = (off <= ws_size);  // fall back to fp32 gather if ws too small

    hipMemsetAsync(deg, 0, (N_NODES + 1) * sizeof(int), stream);

    k_deg<<<NB_DEG, 256, 0, stream>>>(erow, deg, rank);

    const int NB = (N_NODES + 255) / 256;  // 391
    k_scan<<<NB, 256, 0, stream>>>(deg, start, deg + N_NODES);

    k_fillpre<<<FILL_BLOCKS + NB_H2B + NB_WCT, 256, 0, stream>>>(
        erow, ecol, rank, start, colidx, h, hb, W, WcT, use_hb ? 1 : 0);

    if (use_hb)
        k_agg<true><<<(N_NODES + 3) / 4, 256, 0, stream>>>(hb, start, deg, colidx, hagg);
    else
        k_agg<false><<<(N_NODES + 3) / 4, 256, 0, stream>>>(h, start, deg, colidx, hagg);

    k_gemm<<<MPAD / BM * 4, 256, 0, stream>>>(hagg, WcT, out, N_NODES);
}